// Round 14
// baseline (133.464 us; speedup 1.0000x reference)
//
#include <hip/hip_runtime.h>
#include <hip/hip_fp16.h>
#include <math.h>

#define N_NODES 50000
#define N_EDGES 800000
#define D_FEAT 64
#define XCHUNKS (N_NODES * D_FEAT / 8)   // 400000 x->f16 chunks (8 elems each)
#define RPB 32                           // rows per block (8 waves * 4 row-groups)
#define NBLK ((N_NODES + RPB - 1) / RPB) // 1563
#define ECAP 1024                        // staged edges/block (8KB); Poisson(512)+22sigma

// ---- f16 helpers ----
__device__ __forceinline__ unsigned pack2h(float a, float b) {
    __half2 h = __floats2half2_rn(a, b);
    return *reinterpret_cast<unsigned*>(&h);
}
__device__ __forceinline__ __half2 as_h2(unsigned u) {
    return *reinterpret_cast<__half2*>(&u);
}

// Fast ELU: native v_exp_f32 (abs threshold 0.765 makes expm1 precision moot).
__device__ __forceinline__ float elu_f(float x) {
    return x > 0.f ? x : (__expf(x) - 1.f);
}

// Prep: row_ptr lower-bound + x (f32) -> f16 table [N][64].
__global__ __launch_bounds__(256) void prep_kernel(const int* __restrict__ rows,
                                                   const float* __restrict__ x,
                                                   int* __restrict__ row_ptr,
                                                   unsigned short* __restrict__ xhf) {
    const int i = blockIdx.x * blockDim.x + threadIdx.x;
    if (i <= N_NODES) {
        int lo = 0, hi = N_EDGES;
        while (lo < hi) {
            int mid = (lo + hi) >> 1;
            if (rows[mid] < i) lo = mid + 1; else hi = mid;
        }
        row_ptr[i] = lo;
    }
    if (i < XCHUNKS) {
        const float4 f0 = *reinterpret_cast<const float4*>(x + (size_t)i * 8);
        const float4 f1 = *reinterpret_cast<const float4*>(x + (size_t)i * 8 + 4);
        uint4 w;
        w.x = pack2h(f0.x, f0.y);
        w.y = pack2h(f0.z, f0.w);
        w.z = pack2h(f1.x, f1.y);
        w.w = pack2h(f1.z, f1.w);
        *reinterpret_cast<uint4*>(xhf + (size_t)i * 8) = w;
    }
}

// One 8-edge step, edge (off, half2 val) sourced from LDS (broadcast reads).
// Proven round-8/10/11 shape: 16 lanes/row, 8B gathers, ~32 VGPR.
template <bool MASKED>
__device__ __forceinline__ void edge_step8_lds(const char* __restrict__ hb,
                                               const int2* __restrict__ elds,
                                               int le, int le1, int boff,
                                               __half2& A0, __half2& A1,
                                               __half2& B0, __half2& B1) {
    int off[8]; unsigned v2[8];
    #pragma unroll
    for (int k = 0; k < 8; ++k) {
        const int t = le + k;
        const int idx = MASKED ? (t < le1 ? t : le1 - 1) : t;
        const int2 p = elds[idx];
        off[k] = p.x;
        v2[k]  = (unsigned)p.y;
        if (MASKED) v2[k] = (t < le1) ? v2[k] : 0u;
    }
    uint2 gg[8];
    #pragma unroll
    for (int k = 0; k < 8; ++k)
        gg[k] = *reinterpret_cast<const uint2*>(hb + (unsigned)(off[k] + boff));
    #pragma unroll
    for (int k = 0; k < 8; ++k) {
        const __half2 vv = as_h2(v2[k]);
        if (k & 1) {
            B0 = __hfma2(vv, as_h2(gg[k].x), B0);
            B1 = __hfma2(vv, as_h2(gg[k].y), B1);
        } else {
            A0 = __hfma2(vv, as_h2(gg[k].x), A0);
            A1 = __hfma2(vv, as_h2(gg[k].y), A1);
        }
    }
}

// SpMM layer over f16 h: 8 waves/block, 4 row-groups/wave (16 lanes per row,
// 4 f16 features per lane = 8B gather; 128B line per edge). Block's contiguous
// edge range staged in LDS from cols/vals (rows sorted).
// !FUSE: h_out is f16 [N_NODES][64].  FUSE: h_out is f32 out = y @ W^T + b.
template <bool FUSE>
__global__ __launch_bounds__(512) void gcn_layer(
    const unsigned short* __restrict__ h_in,  // f16 [N_NODES][64]
    const int*   __restrict__ cols,
    const float* __restrict__ vals,
    const int*   __restrict__ row_ptr,
    const float* __restrict__ scalar_p,
    const float* __restrict__ W,        // [64,64] (FUSE only)
    const float* __restrict__ bvec,     // [64]    (FUSE only)
    void*        __restrict__ h_out)
{
    __shared__ int2     elds[ECAP];                  // 8 KB staged edges
    __shared__ unsigned Wh[FUSE ? 64 * 33 : 1];      // 8.4 KB f16 W pairs
    __shared__ float    ylds[FUSE ? 8 * 4 * 68 : 1]; // 8.7 KB [wave][row][68 pad]

    const int tid  = threadIdx.x;
    const int lane = tid & 63;
    const int wave = tid >> 6;           // 0..7
    const int g    = lane >> 4;          // row-group 0..3
    const int f4   = lane & 15;          // 8B feature chunk index
    const int boff = f4 * 8;             // byte offset of this lane's chunk

    // Stage this block's contiguous edge range: (col*128, half2{v,v}).
    const int rb   = blockIdx.x * RPB;
    const int rtop = (rb + RPB < N_NODES) ? rb + RPB : N_NODES;
    const int eb0  = row_ptr[rb];
    const int eb1  = row_ptr[rtop];
    const int cnt  = min(eb1 - eb0, ECAP);
    for (int i = tid; i < cnt; i += 512) {
        const int   c = cols[eb0 + i];
        const float v = vals[eb0 + i];
        elds[i] = make_int2(c << 7, (int)pack2h(v, v));
    }
    if constexpr (FUSE) {
        for (int i = tid; i < 64 * 32; i += 512) {
            const int j = i >> 5, c = i & 31;
            Wh[j * 33 + c] = pack2h(W[j * 64 + 2 * c], W[j * 64 + 2 * c + 1]);
        }
    }
    __syncthreads();

    const int row = rb + wave * 4 + g;
    const float s = scalar_p[0];
    int e0 = 0, e1 = 0;
    if (row < N_NODES) { e0 = row_ptr[row]; e1 = row_ptr[row + 1]; }
    const char* hb = (const char*)h_in;

    __half2 A0 = __floats2half2_rn(0.f, 0.f);
    __half2 A1 = A0, B0 = A0, B1 = A0;

    // Staged window (virtually always the whole row).
    const int ecap = eb0 + cnt;
    const int le0 = e0 - eb0;
    const int le1 = (e1 < ecap ? e1 : ecap) - eb0;
    int le = le0;
    for (; le + 8 <= le1; le += 8)
        edge_step8_lds<false>(hb, elds, le, le1, boff, A0, A1, B0, B1);
    if (le < le1)
        edge_step8_lds<true>(hb, elds, le, le1, boff, A0, A1, B0, B1);
    // Overflow beyond staged capacity (essentially never): scalar global path.
    for (int e = (e0 > ecap ? e0 : ecap); e < e1; ++e) {
        const int   c = cols[e];
        const float v = vals[e];
        const __half2 vv = as_h2(pack2h(v, v));
        const uint2 gg = *reinterpret_cast<const uint2*>(hb + (unsigned)((c << 7) + boff));
        A0 = __hfma2(vv, as_h2(gg.x), A0);
        A1 = __hfma2(vv, as_h2(gg.y), A1);
    }

    // Convert to f32, combine A+B chains, scale + ELU.
    const float2 a0 = __half22float2(A0), a1 = __half22float2(A1);
    const float2 b0 = __half22float2(B0), b1 = __half22float2(B1);
    float4 acc;
    acc.x = elu_f((a0.x + b0.x) * s);
    acc.y = elu_f((a0.y + b0.y) * s);
    acc.z = elu_f((a1.x + b1.x) * s);
    acc.w = elu_f((a1.y + b1.y) * s);

    if constexpr (!FUSE) {
        if (row < N_NODES) {
            uint2 wv;
            wv.x = pack2h(acc.x, acc.y);
            wv.y = pack2h(acc.z, acc.w);
            *reinterpret_cast<uint2*>((char*)h_out + (size_t)row * 128 + boff) = wv;
        }
    } else {
        float* yw = ylds + wave * (4 * 68);
        *reinterpret_cast<float4*>(yw + g * 68 + f4 * 4) = acc;
        asm volatile("s_waitcnt lgkmcnt(0)" ::: "memory");  // same-wave ds ordering

        const int j = lane;
        const float bj = bvec[j];
        float o0 = bj, o1 = bj, o2 = bj, o3 = bj;
        #pragma unroll
        for (int d0 = 0; d0 < 16; ++d0) {
            const float2 wA = __half22float2(as_h2(Wh[j * 33 + 2 * d0]));
            const float2 wB = __half22float2(as_h2(Wh[j * 33 + 2 * d0 + 1]));
            const float4 y0 = *reinterpret_cast<const float4*>(yw + 0 * 68 + d0 * 4);
            const float4 y1 = *reinterpret_cast<const float4*>(yw + 1 * 68 + d0 * 4);
            const float4 y2 = *reinterpret_cast<const float4*>(yw + 2 * 68 + d0 * 4);
            const float4 y3 = *reinterpret_cast<const float4*>(yw + 3 * 68 + d0 * 4);
            o0 = fmaf(y0.x, wA.x, o0); o0 = fmaf(y0.y, wA.y, o0);
            o0 = fmaf(y0.z, wB.x, o0); o0 = fmaf(y0.w, wB.y, o0);
            o1 = fmaf(y1.x, wA.x, o1); o1 = fmaf(y1.y, wA.y, o1);
            o1 = fmaf(y1.z, wB.x, o1); o1 = fmaf(y1.w, wB.y, o1);
            o2 = fmaf(y2.x, wA.x, o2); o2 = fmaf(y2.y, wA.y, o2);
            o2 = fmaf(y2.z, wB.x, o2); o2 = fmaf(y2.w, wB.y, o2);
            o3 = fmaf(y3.x, wA.x, o3); o3 = fmaf(y3.y, wA.y, o3);
            o3 = fmaf(y3.z, wB.x, o3); o3 = fmaf(y3.w, wB.y, o3);
        }
        const int rbase = rb + wave * 4;
        float* outp = (float*)h_out;
        if (rbase + 0 < N_NODES) outp[(size_t)(rbase + 0) * D_FEAT + j] = o0;
        if (rbase + 1 < N_NODES) outp[(size_t)(rbase + 1) * D_FEAT + j] = o1;
        if (rbase + 2 < N_NODES) outp[(size_t)(rbase + 2) * D_FEAT + j] = o2;
        if (rbase + 3 < N_NODES) outp[(size_t)(rbase + 3) * D_FEAT + j] = o3;
    }
}

extern "C" void kernel_launch(void* const* d_in, const int* in_sizes, int n_in,
                              void* d_out, int out_size, void* d_ws, size_t ws_size,
                              hipStream_t stream) {
    const float* x       = (const float*)d_in[0];
    const int*   rows    = (const int*)  d_in[1];
    const int*   cols    = (const int*)  d_in[2];
    const float* vals    = (const float*)d_in[3];
    const float* scalars = (const float*)d_in[4];
    const float* W       = (const float*)d_in[5];
    const float* b       = (const float*)d_in[6];
    float* out = (float*)d_out;

    // ws layout: row_ptr | xhf (f16) | h1 (f16)   (~13 MB total)
    const size_t rp_b = (sizeof(int) * (N_NODES + 1) + 255) & ~size_t(255);
    const size_t xb_b = ((size_t)N_NODES * D_FEAT * 2 + 255) & ~size_t(255);

    int*            row_ptr = (int*)d_ws;
    unsigned short* xhf     = (unsigned short*)((char*)d_ws + rp_b);
    unsigned short* h1      = (unsigned short*)((char*)d_ws + rp_b + xb_b);

    prep_kernel<<<(XCHUNKS + 255) / 256, 256, 0, stream>>>(rows, x, row_ptr, xhf);

    gcn_layer<false><<<NBLK, 512, 0, stream>>>(
        xhf, cols, vals, row_ptr, scalars + 0, nullptr, nullptr, h1);
    gcn_layer<true><<<NBLK, 512, 0, stream>>>(
        h1, cols, vals, row_ptr, scalars + 1, W, b, out);
}

// Round 15
// 48.841 us; speedup vs baseline: 2.7326x; 2.7326x over previous
//
#include <hip/hip_runtime.h>
#include <hip/hip_fp16.h>
#include <math.h>

#define N_NODES 50000
#define N_EDGES 800000
#define D_FEAT 64
#define XCHUNKS (N_NODES * D_FEAT / 8)   // 400000 x->f16 chunks (8 elems each)
#define NBLK 3125                        // 16 rows/block * 3125 = 50000 exactly
#define ECAP 512                         // staged edges per block (4KB LDS); Poisson(256) -> ~never exceeded

// ---- f16 helpers ----
__device__ __forceinline__ unsigned pack2h(float a, float b) {
    __half2 h = __floats2half2_rn(a, b);
    return *reinterpret_cast<unsigned*>(&h);
}
__device__ __forceinline__ __half2 as_h2(unsigned u) {
    return *reinterpret_cast<__half2*>(&u);
}

// Fast ELU: native v_exp_f32 (abs threshold 0.765 makes expm1 precision moot).
__device__ __forceinline__ float elu_f(float x) {
    return x > 0.f ? x : (__expf(x) - 1.f);
}

// Prep: row_ptr lower-bound + x (f32) -> f16 table. No edge packing anymore
// (edges are staged into LDS by the layer kernels directly from cols/vals).
__global__ __launch_bounds__(256) void prep_kernel(const int* __restrict__ rows,
                                                   const float* __restrict__ x,
                                                   int* __restrict__ row_ptr,
                                                   unsigned short* __restrict__ xhf) {
    const int i = blockIdx.x * blockDim.x + threadIdx.x;
    if (i <= N_NODES) {
        int lo = 0, hi = N_EDGES;
        while (lo < hi) {
            int mid = (lo + hi) >> 1;
            if (rows[mid] < i) lo = mid + 1; else hi = mid;
        }
        row_ptr[i] = lo;
    }
    if (i < XCHUNKS) {
        const float4 f0 = *reinterpret_cast<const float4*>(x + (size_t)i * 8);
        const float4 f1 = *reinterpret_cast<const float4*>(x + (size_t)i * 8 + 4);
        uint4 w;
        w.x = pack2h(f0.x, f0.y);
        w.y = pack2h(f0.z, f0.w);
        w.z = pack2h(f1.x, f1.y);
        w.w = pack2h(f1.z, f1.w);
        *reinterpret_cast<uint4*>(xhf + (size_t)i * 8) = w;
    }
}

// One 8-edge step, edge (off, half2 val) sourced from LDS (broadcast reads).
// Gather/fma shape identical to the proven round-8/10 kernel.
template <bool MASKED>
__device__ __forceinline__ void edge_step8_lds(const char* __restrict__ hb,
                                               const int2* __restrict__ elds,
                                               int le, int le1, int boff,
                                               __half2& A0, __half2& A1,
                                               __half2& B0, __half2& B1) {
    int off[8]; unsigned v2[8];
    #pragma unroll
    for (int k = 0; k < 8; ++k) {
        const int t = le + k;
        const int idx = MASKED ? (t < le1 ? t : le1 - 1) : t;
        const int2 p = elds[idx];
        off[k] = p.x;
        v2[k]  = (unsigned)p.y;
        if (MASKED) v2[k] = (t < le1) ? v2[k] : 0u;
    }
    uint2 gg[8];
    #pragma unroll
    for (int k = 0; k < 8; ++k)
        gg[k] = *reinterpret_cast<const uint2*>(hb + (unsigned)(off[k] + boff));
    #pragma unroll
    for (int k = 0; k < 8; ++k) {
        const __half2 vv = as_h2(v2[k]);
        if (k & 1) {
            B0 = __hfma2(vv, as_h2(gg[k].x), B0);
            B1 = __hfma2(vv, as_h2(gg[k].y), B1);
        } else {
            A0 = __hfma2(vv, as_h2(gg[k].x), A0);
            A1 = __hfma2(vv, as_h2(gg[k].y), A1);
        }
    }
}

// SpMM layer over f16 h: 4 waves/block, 4 row-groups/wave (16 lanes per row,
// 4 f16 features per lane = 8B gather; 128B line per edge). Block's contiguous
// edge range staged in LDS from cols/vals (rows sorted).
// !FUSE: h_out is f16 [N_NODES][64].  FUSE: h_out is f32 out = y @ W^T + b,
// with W staged in LDS as f16 pairs (stride-33 uint: conflict-free, 8.4KB).
template <bool FUSE>
__global__ __launch_bounds__(256) void gcn_layer(
    const unsigned short* __restrict__ h_in,  // f16 [N_NODES][64]
    const int*   __restrict__ cols,
    const float* __restrict__ vals,
    const int*   __restrict__ row_ptr,
    const float* __restrict__ scalar_p,
    const float* __restrict__ W,        // [64,64] (FUSE only)
    const float* __restrict__ bvec,     // [64]    (FUSE only)
    void*        __restrict__ h_out)
{
    __shared__ int2     elds[ECAP];                  // 4 KB staged edges
    __shared__ unsigned Wh[FUSE ? 64 * 33 : 1];      // 8.4 KB f16 W pairs
    __shared__ float    ylds[FUSE ? 4 * 4 * 68 : 1]; // 4.3 KB [wave][row][68]

    const int tid  = threadIdx.x;
    const int lane = tid & 63;
    const int wave = tid >> 6;
    const int g    = lane >> 4;          // row-group 0..3
    const int f4   = lane & 15;          // 8B feature chunk index
    const int boff = f4 * 8;             // byte offset of this lane's chunk

    // Stage this block's contiguous edge range: (col*128, half2{v,v}).
    const int rb  = blockIdx.x * 16;
    const int eb0 = row_ptr[rb];
    const int eb1 = row_ptr[rb + 16];
    const int cnt = min(eb1 - eb0, ECAP);
    for (int i = tid; i < cnt; i += 256) {
        const int   c = cols[eb0 + i];
        const float v = vals[eb0 + i];
        elds[i] = make_int2(c << 7, (int)pack2h(v, v));
    }
    if constexpr (FUSE) {
        for (int i = tid; i < 64 * 32; i += 256) {
            const int j = i >> 5, c = i & 31;
            Wh[j * 33 + c] = pack2h(W[j * 64 + 2 * c], W[j * 64 + 2 * c + 1]);
        }
    }
    __syncthreads();

    const int row = rb + wave * 4 + g;
    const float s  = scalar_p[0];
    const int  e0  = row_ptr[row];
    const int  e1  = row_ptr[row + 1];
    const char* hb = (const char*)h_in;

    __half2 A0 = __floats2half2_rn(0.f, 0.f);
    __half2 A1 = A0, B0 = A0, B1 = A0;

    // Staged window (virtually always the whole row).
    const int ecap = eb0 + cnt;
    const int le0 = e0 - eb0;
    const int le1 = (e1 < ecap ? e1 : ecap) - eb0;
    int le = le0;
    for (; le + 8 <= le1; le += 8)
        edge_step8_lds<false>(hb, elds, le, le1, boff, A0, A1, B0, B1);
    if (le < le1)
        edge_step8_lds<true>(hb, elds, le, le1, boff, A0, A1, B0, B1);
    // Overflow beyond staged capacity (essentially never): scalar global path.
    for (int e = (e0 > ecap ? e0 : ecap); e < e1; ++e) {
        const int   c = cols[e];
        const float v = vals[e];
        const __half2 vv = as_h2(pack2h(v, v));
        const uint2 gg = *reinterpret_cast<const uint2*>(hb + (unsigned)((c << 7) + boff));
        A0 = __hfma2(vv, as_h2(gg.x), A0);
        A1 = __hfma2(vv, as_h2(gg.y), A1);
    }

    // Convert to f32, combine A+B chains, scale + ELU.
    const float2 a0 = __half22float2(A0), a1 = __half22float2(A1);
    const float2 b0 = __half22float2(B0), b1 = __half22float2(B1);
    float4 acc;
    acc.x = elu_f((a0.x + b0.x) * s);
    acc.y = elu_f((a0.y + b0.y) * s);
    acc.z = elu_f((a1.x + b1.x) * s);
    acc.w = elu_f((a1.y + b1.y) * s);

    if constexpr (!FUSE) {
        uint2 wv;
        wv.x = pack2h(acc.x, acc.y);
        wv.y = pack2h(acc.z, acc.w);
        *reinterpret_cast<uint2*>((char*)h_out + (size_t)row * 128 + boff) = wv;
    } else {
        float* yw = ylds + wave * (4 * 68);
        *reinterpret_cast<float4*>(yw + g * 68 + f4 * 4) = acc;
        asm volatile("s_waitcnt lgkmcnt(0)" ::: "memory");  // same-wave ds ordering

        const int j = lane;
        const float bj = bvec[j];
        float o0 = bj, o1 = bj, o2 = bj, o3 = bj;
        #pragma unroll
        for (int d0 = 0; d0 < 16; ++d0) {
            // W features 4d0..4d0+3 for out j: two f16 pairs, conflict-free.
            const float2 wA = __half22float2(as_h2(Wh[j * 33 + 2 * d0]));
            const float2 wB = __half22float2(as_h2(Wh[j * 33 + 2 * d0 + 1]));
            const float4 y0 = *reinterpret_cast<const float4*>(yw + 0 * 68 + d0 * 4);
            const float4 y1 = *reinterpret_cast<const float4*>(yw + 1 * 68 + d0 * 4);
            const float4 y2 = *reinterpret_cast<const float4*>(yw + 2 * 68 + d0 * 4);
            const float4 y3 = *reinterpret_cast<const float4*>(yw + 3 * 68 + d0 * 4);
            o0 = fmaf(y0.x, wA.x, o0); o0 = fmaf(y0.y, wA.y, o0);
            o0 = fmaf(y0.z, wB.x, o0); o0 = fmaf(y0.w, wB.y, o0);
            o1 = fmaf(y1.x, wA.x, o1); o1 = fmaf(y1.y, wA.y, o1);
            o1 = fmaf(y1.z, wB.x, o1); o1 = fmaf(y1.w, wB.y, o1);
            o2 = fmaf(y2.x, wA.x, o2); o2 = fmaf(y2.y, wA.y, o2);
            o2 = fmaf(y2.z, wB.x, o2); o2 = fmaf(y2.w, wB.y, o2);
            o3 = fmaf(y3.x, wA.x, o3); o3 = fmaf(y3.y, wA.y, o3);
            o3 = fmaf(y3.z, wB.x, o3); o3 = fmaf(y3.w, wB.y, o3);
        }
        const size_t rbase = (size_t)(rb + wave * 4) * D_FEAT;
        float* outp = (float*)h_out;
        outp[rbase + 0 * D_FEAT + j] = o0;
        outp[rbase + 1 * D_FEAT + j] = o1;
        outp[rbase + 2 * D_FEAT + j] = o2;
        outp[rbase + 3 * D_FEAT + j] = o3;
    }
}

extern "C" void kernel_launch(void* const* d_in, const int* in_sizes, int n_in,
                              void* d_out, int out_size, void* d_ws, size_t ws_size,
                              hipStream_t stream) {
    const float* x       = (const float*)d_in[0];
    const int*   rows    = (const int*)  d_in[1];
    const int*   cols    = (const int*)  d_in[2];
    const float* vals    = (const float*)d_in[3];
    const float* scalars = (const float*)d_in[4];
    const float* W       = (const float*)d_in[5];
    const float* b       = (const float*)d_in[6];
    float* out = (float*)d_out;

    // ws layout: row_ptr | xhf (f16) | h1 (f16)   (~13 MB total)
    const size_t rp_b = (sizeof(int) * (N_NODES + 1) + 255) & ~size_t(255);
    const size_t xb_b = ((size_t)N_NODES * D_FEAT * 2 + 255) & ~size_t(255);

    int*            row_ptr = (int*)d_ws;
    unsigned short* xhf     = (unsigned short*)((char*)d_ws + rp_b);
    unsigned short* h1      = (unsigned short*)((char*)d_ws + rp_b + xb_b);

    prep_kernel<<<(XCHUNKS + 255) / 256, 256, 0, stream>>>(rows, x, row_ptr, xhf);

    gcn_layer<false><<<NBLK, 256, 0, stream>>>(
        xhf, cols, vals, row_ptr, scalars + 0, nullptr, nullptr, h1);
    gcn_layer<true><<<NBLK, 256, 0, stream>>>(
        h1, cols, vals, row_ptr, scalars + 1, W, b, out);
}